// Round 1
// baseline (137.683 us; speedup 1.0000x reference)
//
#include <hip/hip_runtime.h>

typedef unsigned char u8;
typedef float f32x4 __attribute__((ext_vector_type(4)));
typedef float f32x16 __attribute__((ext_vector_type(16)));

#define LL 4096
#define PSTR 136              // P row stride (bytes): 2-lane/bank writes (free), validated R5
#define SCALE 16.0f           // x pre-scale before fp8
#define GSCALE (1.0f/256.0f)  // undo SCALE^2 on the gram
#define FREQC (-0.03597789207803197f)   // -ln(10000)/256

__device__ __forceinline__ long LCAST(uint2 v) { return __builtin_bit_cast(long, v); }

typedef __attribute__((address_space(3))) u8 lds_u8;
typedef __attribute__((address_space(1))) u8 glb_u8;
__device__ __forceinline__ void dma16(const u8* g, u8* l) {
  __builtin_amdgcn_global_load_lds((const glb_u8*)g, (lds_u8*)l, 16, 0, 0);
}

// ---------------- prep2: fp8 convert + swizzled layouts, COALESCED xT transpose ----------------
// Produces bit-identical layouts to the validated R5-R7 prep1:
//   xbf: row r (256 B): 8-B chunk c stored at ((c ^ (r&31))*8).
//   xT : d-row (4096 B) split into 32 j-segments of 128 B; chunk c (rows 8c..8c+7 of the
//        segment) at byte ((c ^ (d&15))*8).
// Key change vs prep1: each block owns 64 j-rows; since the chunk swizzle XORs c (3 bits used
// within a 64-row half-segment) with d&15, a half-segment lands in a CONTIGUOUS 64-B half of
// the 128-B segment (which half = (ch&1)^bit3(d)). So xT writes become 64-B bursts instead of
// scattered 8-B stores (prep1's 524K scattered stores were the ~50 us).
// 256 blocks (4 b x 64 chunks) x 512 thr = 1 block/CU.
__global__ __launch_bounds__(512) void prep2(const float* __restrict__ x, u8* __restrict__ xbf,
                                             u8* __restrict__ xT, float* __restrict__ sq) {
  __shared__ u8 T2[256 * 72];       // col-major fp8: T2[d*72 + local_row], 8-B pad per column
  const int blk = blockIdx.x;
  const int b = blk >> 6, ch = blk & 63;
  const int j0 = ch << 6;           // first of this block's 64 rows
  const int tid = threadIdx.x;
  const int wv = tid >> 6, ln = tid & 63;
  const long bL = (long)b * LL;
  const float4* x4 = (const float4*)x + (bL + j0) * 64;
  unsigned* xb4 = (unsigned*)xbf + (bL + j0) * 64;

  #pragma unroll
  for (int g = 0; g < 2; ++g) {
    int pkw[4];
    #pragma unroll
    for (int ii = 0; ii < 4; ++ii) {
      const int row = 8 * wv + 4 * g + ii;                 // 0..63, wave owns 8 consecutive rows
      float4 v = x4[row * 64 + ln];                        // 1 KB contiguous per wave
      float s = v.x * v.x + v.y * v.y + v.z * v.z + v.w * v.w;
      #pragma unroll
      for (int o = 32; o; o >>= 1) s += __shfl_xor(s, o);
      if (ln == 0) sq[bL + j0 + row] = s;
      int pk = __builtin_amdgcn_cvt_pk_fp8_f32(v.x * SCALE, v.y * SCALE, 0, false);
      pk = __builtin_amdgcn_cvt_pk_fp8_f32(v.z * SCALE, v.w * SCALE, pk, true);
      const int sdw = (((ln >> 1) ^ ((j0 + row) & 31)) << 1) | (ln & 1);
      xb4[row * 64 + sdw] = (unsigned)pk;                  // 256-B coalesced per wave
      pkw[ii] = pk;
    }
    // 4x4 byte transpose in registers (v_perm_b32), then dword writes into col-major T2.
    const int rb = 8 * wv + 4 * g;                         // first of 4 consecutive rows
    #pragma unroll
    for (int k = 0; k < 4; ++k) {
      const unsigned sel = (unsigned)(k | ((4 + k) << 8));
      unsigned m01 = __builtin_amdgcn_perm((unsigned)pkw[1], (unsigned)pkw[0], sel);
      unsigned m23 = __builtin_amdgcn_perm((unsigned)pkw[3], (unsigned)pkw[2], sel);
      unsigned tw  = __builtin_amdgcn_perm(m23, m01, 0x05040100u);
      // tw bytes = rows rb..rb+3 at dim 4*ln+k
      *(unsigned*)(T2 + (4 * ln + k) * 72 + rb) = tw;
    }
  }
  __syncthreads();
  // Phase 2: per d-row, emit the contiguous 64-B half-segment this block owns.
  #pragma unroll
  for (int db = 0; db < 2; ++db) {
    const int d = db * 128 + (tid >> 2);
    const int oct2 = tid & 3;                              // which 16-B piece of the 64-B half
    const int key = d & 15;
    const int hb = ((ch & 1) << 3) ^ (key & 8);            // position-half base (0 or 8)
    const int p0 = hb + 2 * oct2;                          // even swizzled position
    const int c0 = (p0 ^ key) & 7;                         // local chunk (8 rows) for p0
    const int c1 = ((p0 + 1) ^ key) & 7;                   // local chunk for p0+1
    uint2 lo = *(const uint2*)(T2 + d * 72 + 8 * c0);
    uint2 hi = *(const uint2*)(T2 + d * 72 + 8 * c1);
    uint4 ov; ov.x = lo.x; ov.y = lo.y; ov.z = hi.x; ov.w = hi.y;
    // wave = 16 d-rows x 64-B contiguous bursts
    *(uint4*)(xT + (((long)(b << 8) + d) << 12) + ((ch >> 1) << 7) + (hb << 3) + (oct2 << 4)) = ov;
  }
}

// ---------------- main fused kernel (UNCHANGED from validated 78 us version) ----------------
// 256 blocks x 512 thr (1 block/CU, 8 waves). Block = (batch, 64 Q rows).
// K-tile 128, 32 iters, ONE barrier/iter. K dbuf LDS (global_load_lds w16, full-iter flight),
// P dbuf LDS, V fragments in dbuf REGISTERS (loaded pre-barrier, consumed post-barrier).
// Iter: [DMA K(it+1) | mm2(it-1): P(it-1)+vf | vf-load(it) | mm1(it): 32-MFMA run | exp->P(it) | barrier].
// mm1 (16x16x32 fp8, S^T): wave w -> j-strip 16w, all 4 Q i-strips (4 chains).
// mm2 (32x32x16 fp8): wave w -> O[64][32w..32w+31].
__global__ __launch_bounds__(512, 2) void tpe_main(
    const u8* __restrict__ xbf, const u8* __restrict__ xT,
    const float* __restrict__ sqv,
    const float* __restrict__ x, float* __restrict__ out) {
  __shared__ u8 Kt[2][32768];    // K tile 128 rows x 256 B (row-swizzled, as xbf)
  __shared__ u8 Ps[2][64 * PSTR];
  __shared__ float lred[8][64];
  __shared__ float linv[64];

  const int tid = threadIdx.x;
  const int w = tid >> 6;
  const int lane = tid & 63;
  const int l15 = lane & 15, l31 = lane & 31;
  const int q4 = lane >> 4;   // 0..3
  const int q2 = lane >> 5;   // 0..1

  // XCD pinning: batch -> XCD pair (2 MB fp8 set stays L2-hot)
  const int blk = blockIdx.x;
  const int b = (blk & 7) >> 1;
  const int qt = ((blk >> 3) << 1) | (blk & 1);
  const int q0 = qt << 6;
  const long bL = (long)b * LL;

  // Q fragments (all 64 rows, 4 chains): 64 VGPRs, from swizzled xbf
  uint2 qf[4][8];
  float qa[4];
  #pragma unroll
  for (int t = 0; t < 4; ++t) {
    const int row = q0 + 16 * t + l15;
    const u8* qrow = xbf + ((bL + row) << 8);
    const int key = row & 31;
    #pragma unroll
    for (int s = 0; s < 8; ++s)
      qf[t][s] = *(const uint2*)(qrow + (((q4 + 4 * s) ^ key) << 3));
    qa[t] = -0.5f * sqv[bL + row];
  }

  f32x16 oacc[2];
  #pragma unroll
  for (int rb = 0; rb < 2; ++rb)
    #pragma unroll
    for (int k = 0; k < 16; ++k) oacc[rb][k] = 0.f;
  float rsacc[4] = {0.f, 0.f, 0.f, 0.f};

  const u8* kbat = xbf + (bL << 8);
  // V segment base for this wave's O columns (d = 32w + l31), swizzled chunks (key = d&15)
  const u8* vseg = xT + (((long)(b << 8) + 32 * w + l31) << 12);
  const int vkey = l31 & 15;

  uint2 vfA[8], vfB[8];

  // prologue: DMA K tile 0 -> Kt[0]
  #pragma unroll
  for (int c = 0; c < 4; ++c) {
    int off = c * 8192 + tid * 16;
    dma16(kbat + off, Kt[0] + off);
  }
  __syncthreads();

#define TPE_ITER(IT, KCUR, KNXT, PPREV, PCUR, VFC, VFN)                                     \
  {                                                                                         \
    const int j0 = (IT) << 7;                                                               \
    if ((IT) < 31) { /* DMA K(it+1): full iteration of flight before the barrier drain */   \
      const u8* ks = kbat + ((long)((IT) + 1) << 15);                                       \
      _Pragma("unroll")                                                                     \
      for (int c = 0; c < 4; ++c) {                                                         \
        int off = c * 8192 + tid * 16;                                                      \
        dma16(ks + off, (KNXT) + off);                                                      \
      }                                                                                     \
    }                                                                                       \
    float4 skv4 = *(const float4*)(sqv + bL + j0 + 16 * w + 4 * q4);                        \
    if ((IT) != 0) { /* mm2 on previous tile: A = P(it-1) LDS, B = vf registers */          \
      _Pragma("unroll")                                                                     \
      for (int s = 0; s < 8; ++s) {                                                         \
        long a0 = *(const long*)((PPREV) + l31 * PSTR + 16 * s + 8 * q2);                   \
        long a1 = *(const long*)((PPREV) + (32 + l31) * PSTR + 16 * s + 8 * q2);            \
        long bv = LCAST(VFC[s]);                                                            \
        oacc[0] = __builtin_amdgcn_mfma_f32_32x32x16_fp8_fp8(a0, bv, oacc[0], 0, 0, 0);     \
        oacc[1] = __builtin_amdgcn_mfma_f32_32x32x16_fp8_fp8(a1, bv, oacc[1], 0, 0, 0);     \
      }                                                                                     \
    }                                                                                       \
    _Pragma("unroll") /* vf for THIS tile (consumed next iter, post-barrier) */             \
    for (int s = 0; s < 8; ++s)                                                             \
      VFN[s] = *(const uint2*)(vseg + j0 + (((2 * s + q2) ^ vkey) << 3));                   \
    { /* mm1: S^T = K.Q^T, 32-MFMA dense run, 4 independent chains */                       \
      const int krow = 16 * w + l15;                                                        \
      const int kkey = krow & 31;                                                           \
      const u8* kb2 = (KCUR) + krow * 256;                                                  \
      f32x4 sacc[4];                                                                        \
      _Pragma("unroll")                                                                     \
      for (int t = 0; t < 4; ++t) {                                                         \
        sacc[t][0] = 0.f; sacc[t][1] = 0.f; sacc[t][2] = 0.f; sacc[t][3] = 0.f;             \
      }                                                                                     \
      _Pragma("unroll")                                                                     \
      for (int s = 0; s < 8; ++s) {                                                         \
        uint2 kf = *(const uint2*)(kb2 + (((q4 + 4 * s) ^ kkey) << 3));                     \
        long av = LCAST(kf);                                                                \
        _Pragma("unroll")                                                                   \
        for (int t = 0; t < 4; ++t)                                                         \
          sacc[t] = __builtin_amdgcn_mfma_f32_16x16x32_fp8_fp8(av, LCAST(qf[t][s]), sacc[t], 0, 0, 0); \
      }                                                                                     \
      _Pragma("unroll") /* P = exp(min(0, g - 0.5||q||^2 - 0.5||k||^2)) -> LDS fp8 */       \
      for (int t = 0; t < 4; ++t) { /* lane: P[i=16t+l15][j=16w+4q4+0..3] */                \
        float p0 = __expf(fminf(fmaf(sacc[t][0], GSCALE, qa[t] + skv4.x), 0.f));            \
        float p1 = __expf(fminf(fmaf(sacc[t][1], GSCALE, qa[t] + skv4.y), 0.f));            \
        float p2 = __expf(fminf(fmaf(sacc[t][2], GSCALE, qa[t] + skv4.z), 0.f));            \
        float p3 = __expf(fminf(fmaf(sacc[t][3], GSCALE, qa[t] + skv4.w), 0.f));            \
        rsacc[t] += (p0 + p1) + (p2 + p3);                                                  \
        int pk = __builtin_amdgcn_cvt_pk_fp8_f32(p0, p1, 0, false);                         \
        pk = __builtin_amdgcn_cvt_pk_fp8_f32(p2, p3, pk, true);                             \
        *(int*)((PCUR) + (16 * t + l15) * PSTR + 16 * w + 4 * q4) = pk;                     \
      }                                                                                     \
    }                                                                                       \
    __syncthreads(); /* the ONLY barrier: P(it) visible, K(it+1) + vf(it) drained */        \
  }

  for (int it2 = 0; it2 < 16; ++it2) {
    TPE_ITER(2 * it2,     Kt[0], Kt[1], Ps[1], Ps[0], vfA, vfB)
    TPE_ITER(2 * it2 + 1, Kt[1], Kt[0], Ps[0], Ps[1], vfB, vfA)
  }
#undef TPE_ITER

  // ---- final mm2 (tile 31: P = Ps[1], V = vfA) ----
  #pragma unroll
  for (int s = 0; s < 8; ++s) {
    long a0 = *(const long*)(Ps[1] + l31 * PSTR + 16 * s + 8 * q2);
    long a1 = *(const long*)(Ps[1] + (32 + l31) * PSTR + 16 * s + 8 * q2);
    long bv = LCAST(vfA[s]);
    oacc[0] = __builtin_amdgcn_mfma_f32_32x32x16_fp8_fp8(a0, bv, oacc[0], 0, 0, 0);
    oacc[1] = __builtin_amdgcn_mfma_f32_32x32x16_fp8_fp8(a1, bv, oacc[1], 0, 0, 0);
  }

  // ---- epilogue: rowsum reduce; out = O/(16*l) + x + pe(inline) ----
  #pragma unroll
  for (int t = 0; t < 4; ++t) {
    float r = rsacc[t];
    r += __shfl_xor(r, 16);
    r += __shfl_xor(r, 32);
    if (lane < 16) lred[w][16 * t + l15] = r;
  }
  __syncthreads();
  if (tid < 64) {
    float s = 0.f;
    #pragma unroll
    for (int ww = 0; ww < 8; ++ww) s += lred[ww][tid];
    linv[tid] = 0.0625f / s;   // 1/16 undoes V pre-scale
  }
  __syncthreads();
  const int col = 32 * w + l31;
  const float freq = __expf((float)(col & ~1) * FREQC);
  #pragma unroll
  for (int rb = 0; rb < 2; ++rb) {
    #pragma unroll
    for (int reg = 0; reg < 16; ++reg) {
      int row = 32 * rb + 4 * q2 + (reg & 3) + 8 * (reg >> 2);
      int l = q0 + row;
      float ang = (float)l * freq;
      float pv = (col & 1) ? __cosf(ang) : __sinf(ang);
      long off = ((bL + l) << 8) + col;
      out[off] = oacc[rb][reg] * linv[row] + x[off] + pv;
    }
  }
}

extern "C" void kernel_launch(void* const* d_in, const int* in_sizes, int n_in,
                              void* d_out, int out_size, void* d_ws, size_t ws_size,
                              hipStream_t stream) {
  const float* x = (const float*)d_in[0];
  float* out = (float*)d_out;
  char* ws = (char*)d_ws;
  u8* xbf = (u8*)ws;                       // 4,194,304 B  (fp8 x, swizzled rows)
  u8* xT = (u8*)(ws + 4194304);            // 4,194,304 B  (fp8 x^T, swizzled segments)
  float* sq = (float*)(ws + 8388608);      //    65,536 B
  prep2<<<256, 512, 0, stream>>>(x, xbf, xT, sq);
  tpe_main<<<256, 512, 0, stream>>>(xbf, xT, sq, x, out);
}